// Round 8
// baseline (273.146 us; speedup 1.0000x reference)
//
#include <hip/hip_runtime.h>
#include <hip/hip_bf16.h>

// Problem constants
#define BB 64
#define CC 96
#define HH 56
#define WW 56
#define HWS 3136          // H*W
#define BC 6144           // B*C
#define HIDDEN 512
#define KS 7
#define KK2 49            // KS*KS
#define K1 3136           // GEMM1 K
#define N1 512            // GEMM1 N
#define EPS 1e-5f

typedef __attribute__((ext_vector_type(8))) short short8;
typedef __attribute__((ext_vector_type(4))) float f32x4;

static __device__ __forceinline__ unsigned short f2bf(float f) {
    union { float f; unsigned int u; } un; un.f = f;
    unsigned int r = un.u + 0x7fffu + ((un.u >> 16) & 1u);
    return (unsigned short)(r >> 16);
}
static __device__ __forceinline__ float bf2f(unsigned short u) {
    union { unsigned int u; float f; } un; un.u = ((unsigned int)u) << 16;
    return un.f;
}

// ---------------------------------------------------------------- LayerNorm
__global__ __launch_bounds__(256) void ln_kernel(const float* __restrict__ x,
                                                 const float* __restrict__ gamma,
                                                 const float* __restrict__ beta,
                                                 unsigned short* __restrict__ a) {
    const int row = blockIdx.x;
    const float4* xr = (const float4*)(x + (size_t)row * HWS);
    float sum = 0.f, sq = 0.f;
    for (int i = threadIdx.x; i < HWS / 4; i += 256) {
        float4 v = xr[i];
        sum += (v.x + v.y) + (v.z + v.w);
        sq = fmaf(v.x, v.x, sq); sq = fmaf(v.y, v.y, sq);
        sq = fmaf(v.z, v.z, sq); sq = fmaf(v.w, v.w, sq);
    }
    #pragma unroll
    for (int off = 32; off > 0; off >>= 1) {
        sum += __shfl_down(sum, off, 64);
        sq  += __shfl_down(sq,  off, 64);
    }
    __shared__ float s1[4], s2[4];
    const int lane = threadIdx.x & 63, wave = threadIdx.x >> 6;
    if (lane == 0) { s1[wave] = sum; s2[wave] = sq; }
    __syncthreads();
    sum = s1[0] + s1[1] + s1[2] + s1[3];
    sq  = s2[0] + s2[1] + s2[2] + s2[3];
    const float mu = sum * (1.f / HWS);
    const float var = fmaf(-mu, mu, sq * (1.f / HWS));
    const float rs = rsqrtf(var + EPS);
    const float4* gr = (const float4*)gamma;
    const float4* br = (const float4*)beta;
    ushort4* ar = (ushort4*)(a + (size_t)row * HWS);
    for (int i = threadIdx.x; i < HWS / 4; i += 256) {
        float4 v = xr[i], g = gr[i], b = br[i];
        ushort4 o;
        o.x = f2bf((v.x - mu) * rs * g.x + b.x);
        o.y = f2bf((v.y - mu) * rs * g.y + b.y);
        o.z = f2bf((v.z - mu) * rs * g.z + b.z);
        o.w = f2bf((v.w - mu) * rs * g.w + b.w);
        ar[i] = o;
    }
}

// ------------------------------------------------- w0 transpose + bf16 cast
__global__ __launch_bounds__(256) void w0t_kernel(const float* __restrict__ w0,
                                                  unsigned short* __restrict__ w0t) {
    __shared__ float tile[64][65];
    const int kb = blockIdx.x * 64;
    const int nb = blockIdx.y * 64;
    for (int i = threadIdx.x; i < 64 * 64; i += 256) {
        int r = i >> 6, c = i & 63;
        tile[r][c] = w0[(size_t)(kb + r) * N1 + nb + c];
    }
    __syncthreads();
    for (int i = threadIdx.x; i < 64 * 64; i += 256) {
        int r = i >> 6, c = i & 63;
        w0t[(size_t)(nb + r) * K1 + kb + c] = f2bf(tile[c][r]);
    }
}

// ------------------------------------------------------------------- GEMM1
// (6144 x 3136)bf16 * (3136 x 512)bf16 [Bt] + b0, exact GELU -> bf16 hidden.
// 64x64 tile, BK=64, 4 waves 2x2 (each 32x32), double-buffered 2-phase.
__global__ __launch_bounds__(256) void gemm1_kernel(const unsigned short* __restrict__ A,
                                                    const unsigned short* __restrict__ Bt,
                                                    const float* __restrict__ b0,
                                                    unsigned short* __restrict__ hidden) {
    __shared__ __align__(16) char smem[32768];  // 2 bufs x (A 8KB | B 8KB)
    const int t = threadIdx.x;
    const int wave = t >> 6, lane = t & 63;
    const int wm = wave >> 1, wn = wave & 1;
    const int tm = blockIdx.x * 64;
    const int tn = blockIdx.y * 64;

    f32x4 acc[2][2] = {};

    auto stage = [&](int buf, int k0) {
        #pragma unroll
        for (int it = 0; it < 2; ++it) {
            int chunk = it * 256 + t;
            int row = chunk >> 3;                   // 0..63, 8 chunks/row
            int cb = (chunk & 7) << 4;              // byte col
            int sb = cb ^ ((row & 7) << 4);         // inverse-swizzled source
            const char* gA = (const char*)(A + (size_t)(tm + row) * K1 + k0) + sb;
            const char* gB = (const char*)(Bt + (size_t)(tn + row) * K1 + k0) + sb;
            char* ldsA = smem + buf * 16384 + it * 4096 + wave * 1024;
            char* ldsB = smem + buf * 16384 + 8192 + it * 4096 + wave * 1024;
            __builtin_amdgcn_global_load_lds(
                (const __attribute__((address_space(1))) unsigned int*)gA,
                (__attribute__((address_space(3))) unsigned int*)ldsA, 16, 0, 0);
            __builtin_amdgcn_global_load_lds(
                (const __attribute__((address_space(1))) unsigned int*)gB,
                (__attribute__((address_space(3))) unsigned int*)ldsB, 16, 0, 0);
        }
    };

    auto compute = [&](int buf) {
        const char* base = smem + buf * 16384;
        #pragma unroll
        for (int kk = 0; kk < 2; ++kk) {
            short8 af[2], bfr[2];
            const int kbase = kk * 64 + ((lane >> 4) << 4);
            #pragma unroll
            for (int i = 0; i < 2; ++i) {
                int row = wm * 32 + i * 16 + (lane & 15);
                af[i] = *(const short8*)(base + row * 128 + (kbase ^ ((row & 7) << 4)));
            }
            #pragma unroll
            for (int j = 0; j < 2; ++j) {
                int row = wn * 32 + j * 16 + (lane & 15);
                bfr[j] = *(const short8*)(base + 8192 + row * 128 + (kbase ^ ((row & 7) << 4)));
            }
            #pragma unroll
            for (int i = 0; i < 2; ++i)
                #pragma unroll
                for (int j = 0; j < 2; ++j)
                    acc[i][j] = __builtin_amdgcn_mfma_f32_16x16x32_bf16(af[i], bfr[j], acc[i][j], 0, 0, 0);
        }
    };

    stage(0, 0);
    __syncthreads();
    int buf = 0;
    for (int ks = 0; ks < 48; ++ks) {
        stage(buf ^ 1, (ks + 1) * 64);
        compute(buf);
        __syncthreads();
        buf ^= 1;
    }
    compute(buf);

    // Epilogue: bias + exact GELU -> bf16. C/D: col=lane&15, row=(lane>>4)*4+r.
    #pragma unroll
    for (int j = 0; j < 2; ++j) {
        const int gc = tn + wn * 32 + j * 16 + (lane & 15);
        const float bias = b0[gc];
        #pragma unroll
        for (int i = 0; i < 2; ++i) {
            #pragma unroll
            for (int r = 0; r < 4; ++r) {
                int gr = tm + wm * 32 + i * 16 + ((lane >> 4) << 2) + r;
                float v = acc[i][j][r] + bias;
                float g = 0.5f * v * (1.0f + erff(v * 0.70710678118f));
                hidden[(size_t)gr * N1 + gc] = f2bf(g);
            }
        }
    }
}

// ------------------------------------------------------------------- GEMM2
// (6144 x 512)bf16 * (512 x 49)f32 + b1. One wave per row, ILP-4 chains.
__global__ __launch_bounds__(256) void gemm2_kernel(const unsigned short* __restrict__ hidden,
                                                    const float* __restrict__ w1,
                                                    const float* __restrict__ b1,
                                                    float* __restrict__ kw) {
    __shared__ unsigned short hs[4][HIDDEN];   // 4 KB
    const int row0 = blockIdx.x * 4;
    if (threadIdx.x < 256) {
        ((short8*)hs)[threadIdx.x] = ((const short8*)(hidden + (size_t)row0 * HIDDEN))[threadIdx.x];
    }
    __syncthreads();
    const int wrow = threadIdx.x >> 6, lane = threadIdx.x & 63;
    const int n = lane < KK2 ? lane : KK2 - 1;
    float a0 = 0.f, a1 = 0.f, a2 = 0.f, a3 = 0.f;
    #pragma unroll 4
    for (int k = 0; k < HIDDEN; k += 4) {
        ushort4 h4 = *(const ushort4*)&hs[wrow][k];   // broadcast read
        a0 = fmaf(bf2f(h4.x), w1[(k    ) * KK2 + n], a0);
        a1 = fmaf(bf2f(h4.y), w1[(k + 1) * KK2 + n], a1);
        a2 = fmaf(bf2f(h4.z), w1[(k + 2) * KK2 + n], a2);
        a3 = fmaf(bf2f(h4.w), w1[(k + 3) * KK2 + n], a3);
    }
    if (lane < KK2)
        kw[(size_t)(row0 + wrow) * KK2 + lane] = (a0 + a1) + (a2 + a3) + b1[lane];
}

// ------------------------------------------------------------ depthwise conv
// 2 planes per block, block=128. Each thread: 7-row x 8-col output tile,
// 13-row sliding window; LDS halo tile 62 rows x 68-float stride per plane.
#define TSTRIDE 68
#define TFLOATS (62 * TSTRIDE)   // 4216 floats per plane
__global__ __launch_bounds__(128) void conv_kernel(const float* __restrict__ x,
                                                   const float* __restrict__ kw,
                                                   const float* __restrict__ attn_bias,
                                                   float* __restrict__ out) {
    __shared__ __align__(16) float tile[2][TFLOATS];
    __shared__ __align__(16) float wsm[2][52];
    const int t = threadIdx.x;
    const int plane0 = blockIdx.x * 2;
    const float* xp = x + (size_t)plane0 * HWS;

    // Stage weights: 2 x 49
    if (t < 98) {
        int p = t / 49, j = t % 49;
        wsm[p][j] = kw[(size_t)(plane0 + p) * KK2 + j];
    }
    // Stage halo tiles: 2 planes x 62 rows x 17 float4 = 2108 float4 slots.
    for (int i = t; i < 2108; i += 128) {
        int p = i / 1054;
        int rem = i - p * 1054;
        int r = rem / 17;
        int c4 = (rem - r * 17) * 4;
        const float* xpp = xp + p * HWS;
        int sr = r - 3;
        float4 v;
        float* vc = (float*)&v;
        #pragma unroll
        for (int j = 0; j < 4; ++j) {
            int sc = c4 + j - 3;
            vc[j] = (sr >= 0 && sr < HH && sc >= 0 && sc < WW) ? xpp[sr * WW + sc] : 0.f;
        }
        *(float4*)&tile[p][r * TSTRIDE + c4] = v;
    }
    __syncthreads();

    if (t < 112) {
        const int p = t / 56;
        const int rem = t - p * 56;
        const int tr = rem / 7;           // 0..7 -> output rows tr*7..tr*7+6
        const int tc = rem - tr * 7;      // 0..6 -> output cols tc*8..tc*8+7
        const int plane = plane0 + p;
        const int c0 = tc * 8;

        float wr[49];
        #pragma unroll
        for (int i = 0; i < 12; ++i) {
            float4 v = *(const float4*)&wsm[p][4 * i];
            wr[4 * i] = v.x; wr[4 * i + 1] = v.y; wr[4 * i + 2] = v.z; wr[4 * i + 3] = v.w;
        }
        wr[48] = wsm[p][48];

        const float bias = attn_bias[plane];
        float acc[7][8];
        #pragma unroll
        for (int o = 0; o < 7; ++o)
            #pragma unroll
            for (int j = 0; j < 8; ++j) acc[o][j] = bias;

        const float* tp = &tile[p][tr * 7 * TSTRIDE + c0];
        #pragma unroll
        for (int ir = 0; ir < 13; ++ir) {
            float rv[14];
            float4 va = *(const float4*)(tp + ir * TSTRIDE);
            float4 vb = *(const float4*)(tp + ir * TSTRIDE + 4);
            float4 vc4 = *(const float4*)(tp + ir * TSTRIDE + 8);
            float2 vd = *(const float2*)(tp + ir * TSTRIDE + 12);
            rv[0] = va.x;  rv[1] = va.y;  rv[2] = va.z;  rv[3] = va.w;
            rv[4] = vb.x;  rv[5] = vb.y;  rv[6] = vb.z;  rv[7] = vb.w;
            rv[8] = vc4.x; rv[9] = vc4.y; rv[10] = vc4.z; rv[11] = vc4.w;
            rv[12] = vd.x; rv[13] = vd.y;
            #pragma unroll
            for (int kr = 0; kr < 7; ++kr) {
                const int o = ir - kr;
                if (o >= 0 && o < 7) {
                    #pragma unroll
                    for (int dc = 0; dc < 7; ++dc) {
                        const float wv = wr[kr * 7 + dc];
                        #pragma unroll
                        for (int j = 0; j < 8; ++j)
                            acc[o][j] = fmaf(rv[dc + j], wv, acc[o][j]);
                    }
                }
            }
        }
        float* op = out + (size_t)plane * HWS + tr * 7 * WW + c0;
        #pragma unroll
        for (int o = 0; o < 7; ++o) {
            float4 v0 = { acc[o][0], acc[o][1], acc[o][2], acc[o][3] };
            float4 v1 = { acc[o][4], acc[o][5], acc[o][6], acc[o][7] };
            *(float4*)(op + o * WW) = v0;
            *(float4*)(op + o * WW + 4) = v1;
        }
    }
}

// ---------------------------------------------------------------------------
extern "C" void kernel_launch(void* const* d_in, const int* in_sizes, int n_in,
                              void* d_out, int out_size, void* d_ws, size_t ws_size,
                              hipStream_t stream) {
    const float* x        = (const float*)d_in[0];
    const float* ln_g     = (const float*)d_in[1];
    const float* ln_b     = (const float*)d_in[2];
    const float* w0       = (const float*)d_in[3];
    const float* b0       = (const float*)d_in[4];
    const float* w1       = (const float*)d_in[5];
    const float* b1       = (const float*)d_in[6];
    const float* attn_b   = (const float*)d_in[7];
    float* out = (float*)d_out;

    char* ws = (char*)d_ws;
    unsigned short* a_bf   = (unsigned short*)ws;                  // 38,535,168 B
    unsigned short* w0t    = (unsigned short*)(ws + 38535168);     //  3,211,264 B
    unsigned short* hidden = (unsigned short*)(ws + 41746432);     //  6,291,456 B (bf16)
    float*          kw     = (float*)(ws + 48037888);              //  1,204,224 B

    hipLaunchKernelGGL(ln_kernel,    dim3(BC),     dim3(256), 0, stream, x, ln_g, ln_b, a_bf);
    hipLaunchKernelGGL(w0t_kernel,   dim3(49, 8),  dim3(256), 0, stream, w0, w0t);
    hipLaunchKernelGGL(gemm1_kernel, dim3(96, 8),  dim3(256), 0, stream, a_bf, w0t, b0, hidden);
    hipLaunchKernelGGL(gemm2_kernel, dim3(BC / 4), dim3(256), 0, stream, hidden, w1, b1, kw);
    hipLaunchKernelGGL(conv_kernel,  dim3(BC / 2), dim3(128), 0, stream, x, kw, attn_b, out);
}

// Round 14
// 263.070 us; speedup vs baseline: 1.0383x; 1.0383x over previous
//
#include <hip/hip_runtime.h>
#include <hip/hip_bf16.h>

// Problem constants
#define BB 64
#define CC 96
#define HH 56
#define WW 56
#define HWS 3136          // H*W
#define BC 6144           // B*C
#define HIDDEN 512
#define KS 7
#define KK2 49            // KS*KS
#define K1 3136           // GEMM1 K
#define N1 512            // GEMM1 N
#define EPS 1e-5f

typedef __attribute__((ext_vector_type(8))) short short8;
typedef __attribute__((ext_vector_type(4))) float f32x4;

static __device__ __forceinline__ unsigned short f2bf(float f) {
    union { float f; unsigned int u; } un; un.f = f;
    unsigned int r = un.u + 0x7fffu + ((un.u >> 16) & 1u);
    return (unsigned short)(r >> 16);
}
static __device__ __forceinline__ float bf2f(unsigned short u) {
    union { unsigned int u; float f; } un; un.u = ((unsigned int)u) << 16;
    return un.f;
}

// ---------------------------------------------------------------- LayerNorm
__global__ __launch_bounds__(256) void ln_kernel(const float* __restrict__ x,
                                                 const float* __restrict__ gamma,
                                                 const float* __restrict__ beta,
                                                 unsigned short* __restrict__ a) {
    const int row = blockIdx.x;
    const float4* xr = (const float4*)(x + (size_t)row * HWS);
    float sum = 0.f, sq = 0.f;
    for (int i = threadIdx.x; i < HWS / 4; i += 256) {
        float4 v = xr[i];
        sum += (v.x + v.y) + (v.z + v.w);
        sq = fmaf(v.x, v.x, sq); sq = fmaf(v.y, v.y, sq);
        sq = fmaf(v.z, v.z, sq); sq = fmaf(v.w, v.w, sq);
    }
    #pragma unroll
    for (int off = 32; off > 0; off >>= 1) {
        sum += __shfl_down(sum, off, 64);
        sq  += __shfl_down(sq,  off, 64);
    }
    __shared__ float s1[4], s2[4];
    const int lane = threadIdx.x & 63, wave = threadIdx.x >> 6;
    if (lane == 0) { s1[wave] = sum; s2[wave] = sq; }
    __syncthreads();
    sum = s1[0] + s1[1] + s1[2] + s1[3];
    sq  = s2[0] + s2[1] + s2[2] + s2[3];
    const float mu = sum * (1.f / HWS);
    const float var = fmaf(-mu, mu, sq * (1.f / HWS));
    const float rs = rsqrtf(var + EPS);
    const float4* gr = (const float4*)gamma;
    const float4* br = (const float4*)beta;
    ushort4* ar = (ushort4*)(a + (size_t)row * HWS);
    for (int i = threadIdx.x; i < HWS / 4; i += 256) {
        float4 v = xr[i], g = gr[i], b = br[i];
        ushort4 o;
        o.x = f2bf((v.x - mu) * rs * g.x + b.x);
        o.y = f2bf((v.y - mu) * rs * g.y + b.y);
        o.z = f2bf((v.z - mu) * rs * g.z + b.z);
        o.w = f2bf((v.w - mu) * rs * g.w + b.w);
        ar[i] = o;
    }
}

// ------------------------------------------------- w0 transpose + bf16 cast
__global__ __launch_bounds__(256) void w0t_kernel(const float* __restrict__ w0,
                                                  unsigned short* __restrict__ w0t) {
    __shared__ float tile[64][65];
    const int kb = blockIdx.x * 64;
    const int nb = blockIdx.y * 64;
    for (int i = threadIdx.x; i < 64 * 64; i += 256) {
        int r = i >> 6, c = i & 63;
        tile[r][c] = w0[(size_t)(kb + r) * N1 + nb + c];
    }
    __syncthreads();
    for (int i = threadIdx.x; i < 64 * 64; i += 256) {
        int r = i >> 6, c = i & 63;
        w0t[(size_t)(nb + r) * K1 + kb + c] = f2bf(tile[c][r]);
    }
}

// ------------------------------------------------------------------- GEMM1
// (6144 x 3136)bf16 * (3136 x 512)bf16 [Bt] + b0, exact GELU -> bf16 hidden.
// 64x64 tile, BK=64, 4 waves 2x2 (each 32x32), double-buffered 2-phase.
__global__ __launch_bounds__(256) void gemm1_kernel(const unsigned short* __restrict__ A,
                                                    const unsigned short* __restrict__ Bt,
                                                    const float* __restrict__ b0,
                                                    unsigned short* __restrict__ hidden) {
    __shared__ __align__(16) char smem[32768];  // 2 bufs x (A 8KB | B 8KB)
    const int t = threadIdx.x;
    const int wave = t >> 6, lane = t & 63;
    const int wm = wave >> 1, wn = wave & 1;
    const int tm = blockIdx.x * 64;
    const int tn = blockIdx.y * 64;

    f32x4 acc[2][2] = {};

    auto stage = [&](int buf, int k0) {
        #pragma unroll
        for (int it = 0; it < 2; ++it) {
            int chunk = it * 256 + t;
            int row = chunk >> 3;                   // 0..63, 8 chunks/row
            int cb = (chunk & 7) << 4;              // byte col
            int sb = cb ^ ((row & 7) << 4);         // inverse-swizzled source
            const char* gA = (const char*)(A + (size_t)(tm + row) * K1 + k0) + sb;
            const char* gB = (const char*)(Bt + (size_t)(tn + row) * K1 + k0) + sb;
            char* ldsA = smem + buf * 16384 + it * 4096 + wave * 1024;
            char* ldsB = smem + buf * 16384 + 8192 + it * 4096 + wave * 1024;
            __builtin_amdgcn_global_load_lds(
                (const __attribute__((address_space(1))) unsigned int*)gA,
                (__attribute__((address_space(3))) unsigned int*)ldsA, 16, 0, 0);
            __builtin_amdgcn_global_load_lds(
                (const __attribute__((address_space(1))) unsigned int*)gB,
                (__attribute__((address_space(3))) unsigned int*)ldsB, 16, 0, 0);
        }
    };

    auto compute = [&](int buf) {
        const char* base = smem + buf * 16384;
        #pragma unroll
        for (int kk = 0; kk < 2; ++kk) {
            short8 af[2], bfr[2];
            const int kbase = kk * 64 + ((lane >> 4) << 4);
            #pragma unroll
            for (int i = 0; i < 2; ++i) {
                int row = wm * 32 + i * 16 + (lane & 15);
                af[i] = *(const short8*)(base + row * 128 + (kbase ^ ((row & 7) << 4)));
            }
            #pragma unroll
            for (int j = 0; j < 2; ++j) {
                int row = wn * 32 + j * 16 + (lane & 15);
                bfr[j] = *(const short8*)(base + 8192 + row * 128 + (kbase ^ ((row & 7) << 4)));
            }
            #pragma unroll
            for (int i = 0; i < 2; ++i)
                #pragma unroll
                for (int j = 0; j < 2; ++j)
                    acc[i][j] = __builtin_amdgcn_mfma_f32_16x16x32_bf16(af[i], bfr[j], acc[i][j], 0, 0, 0);
        }
    };

    stage(0, 0);
    __syncthreads();
    int buf = 0;
    for (int ks = 0; ks < 48; ++ks) {
        stage(buf ^ 1, (ks + 1) * 64);
        compute(buf);
        __syncthreads();
        buf ^= 1;
    }
    compute(buf);

    // Epilogue: bias + exact GELU -> bf16. C/D: col=lane&15, row=(lane>>4)*4+r.
    #pragma unroll
    for (int j = 0; j < 2; ++j) {
        const int gc = tn + wn * 32 + j * 16 + (lane & 15);
        const float bias = b0[gc];
        #pragma unroll
        for (int i = 0; i < 2; ++i) {
            #pragma unroll
            for (int r = 0; r < 4; ++r) {
                int gr = tm + wm * 32 + i * 16 + ((lane >> 4) << 2) + r;
                float v = acc[i][j][r] + bias;
                float g = 0.5f * v * (1.0f + erff(v * 0.70710678118f));
                hidden[(size_t)gr * N1 + gc] = f2bf(g);
            }
        }
    }
}

// ------------------------------------------------------------------- GEMM2
// (6144 x 512)bf16 * (512 x 49)f32 + b1. One wave per row, ILP-4 chains.
__global__ __launch_bounds__(256) void gemm2_kernel(const unsigned short* __restrict__ hidden,
                                                    const float* __restrict__ w1,
                                                    const float* __restrict__ b1,
                                                    float* __restrict__ kw) {
    __shared__ unsigned short hs[4][HIDDEN];   // 4 KB
    const int row0 = blockIdx.x * 4;
    if (threadIdx.x < 256) {
        ((short8*)hs)[threadIdx.x] = ((const short8*)(hidden + (size_t)row0 * HIDDEN))[threadIdx.x];
    }
    __syncthreads();
    const int wrow = threadIdx.x >> 6, lane = threadIdx.x & 63;
    const int n = lane < KK2 ? lane : KK2 - 1;
    float a0 = 0.f, a1 = 0.f, a2 = 0.f, a3 = 0.f;
    #pragma unroll 4
    for (int k = 0; k < HIDDEN; k += 4) {
        ushort4 h4 = *(const ushort4*)&hs[wrow][k];   // broadcast read
        a0 = fmaf(bf2f(h4.x), w1[(k    ) * KK2 + n], a0);
        a1 = fmaf(bf2f(h4.y), w1[(k + 1) * KK2 + n], a1);
        a2 = fmaf(bf2f(h4.z), w1[(k + 2) * KK2 + n], a2);
        a3 = fmaf(bf2f(h4.w), w1[(k + 3) * KK2 + n], a3);
    }
    if (lane < KK2)
        kw[(size_t)(row0 + wrow) * KK2 + lane] = (a0 + a1) + (a2 + a3) + b1[lane];
}

// ------------------------------------------------------------ depthwise conv
// 2 planes per block, 256 threads (R7 structure). LDS tile as float4 slots:
// 62 rows x 17 slots; logical slot c4 of row r stored at physical c4^(r&7)
// (slots 0..15; slot 16 pad, never read). Both-sides XOR swizzle spreads
// each wave's reads across all 8 bank-groups (was ~8-way clustered).
// Each thread: 7-row x 4-col output tile, 13-row sliding window.
#define NSLOT 17
__global__ __launch_bounds__(256) void conv_kernel(const float* __restrict__ x,
                                                   const float* __restrict__ kw,
                                                   const float* __restrict__ attn_bias,
                                                   float* __restrict__ out) {
    __shared__ __align__(16) float4 tile4[2][62 * NSLOT];
    __shared__ __align__(16) float wsm[2][52];
    const int t = threadIdx.x;
    const int plane0 = blockIdx.x * 2;
    const float* xp = x + (size_t)plane0 * HWS;

    // Stage weights: 2 x 49
    if (t < 98) {
        int p = t / 49, j = t % 49;
        wsm[p][j] = kw[(size_t)(plane0 + p) * KK2 + j];
    }
    // Stage halo tiles: 2 planes x 62 rows x 17 float4 slots = 2108 slots.
    for (int i = t; i < 2108; i += 256) {
        int p = i / 1054;
        int rem = i - p * 1054;
        int r = rem / 17;
        int c4 = rem - r * 17;
        const float* xpp = xp + p * HWS;
        int sr = r - 3;
        float4 v;
        float* vc = (float*)&v;
        #pragma unroll
        for (int j = 0; j < 4; ++j) {
            int sc = c4 * 4 + j - 3;
            vc[j] = (sr >= 0 && sr < HH && sc >= 0 && sc < WW) ? xpp[sr * WW + sc] : 0.f;
        }
        int sl = (c4 < 16) ? (c4 ^ (r & 7)) : 16;   // write-side swizzle
        tile4[p][r * NSLOT + sl] = v;
    }
    __syncthreads();

    if (t < 224) {
        const int p = t / 112;
        const int idx = t - p * 112;
        const int tr = idx / 14;          // 0..7 -> output rows tr*7..tr*7+6
        const int tc = idx - tr * 14;     // 0..13 -> output cols tc*4..tc*4+3

        const int plane = plane0 + p;

        float wr[49];
        #pragma unroll
        for (int i = 0; i < 12; ++i) {
            float4 v = *(const float4*)&wsm[p][4 * i];
            wr[4 * i] = v.x; wr[4 * i + 1] = v.y; wr[4 * i + 2] = v.z; wr[4 * i + 3] = v.w;
        }
        wr[48] = wsm[p][48];

        const float bias = attn_bias[plane];
        float acc[7][4];
        #pragma unroll
        for (int o = 0; o < 7; ++o)
            #pragma unroll
            for (int j = 0; j < 4; ++j) acc[o][j] = bias;

        #pragma unroll
        for (int ir = 0; ir < 13; ++ir) {
            const int rr = tr * 7 + ir;               // tile row (0..61)
            const float4* rowp = &tile4[p][rr * NSLOT];
            const int x7 = rr & 7;                    // read-side swizzle
            float4 va  = rowp[tc ^ x7];
            float4 vb  = rowp[(tc + 1) ^ x7];
            float4 vc4 = rowp[(tc + 2) ^ x7];
            float rv[10];
            rv[0] = va.x; rv[1] = va.y; rv[2] = va.z; rv[3] = va.w;
            rv[4] = vb.x; rv[5] = vb.y; rv[6] = vb.z; rv[7] = vb.w;
            rv[8] = vc4.x; rv[9] = vc4.y;
            #pragma unroll
            for (int kr = 0; kr < 7; ++kr) {
                const int o = ir - kr;
                if (o >= 0 && o < 7) {
                    #pragma unroll
                    for (int dc = 0; dc < 7; ++dc) {
                        float wv = wr[kr * 7 + dc];
                        acc[o][0] = fmaf(rv[dc],     wv, acc[o][0]);
                        acc[o][1] = fmaf(rv[dc + 1], wv, acc[o][1]);
                        acc[o][2] = fmaf(rv[dc + 2], wv, acc[o][2]);
                        acc[o][3] = fmaf(rv[dc + 3], wv, acc[o][3]);
                    }
                }
            }
        }
        float* op = out + (size_t)plane * HWS + tr * 7 * WW + tc * 4;
        #pragma unroll
        for (int o = 0; o < 7; ++o) {
            float4 v = { acc[o][0], acc[o][1], acc[o][2], acc[o][3] };
            *(float4*)(op + o * WW) = v;
        }
    }
}

// ---------------------------------------------------------------------------
extern "C" void kernel_launch(void* const* d_in, const int* in_sizes, int n_in,
                              void* d_out, int out_size, void* d_ws, size_t ws_size,
                              hipStream_t stream) {
    const float* x        = (const float*)d_in[0];
    const float* ln_g     = (const float*)d_in[1];
    const float* ln_b     = (const float*)d_in[2];
    const float* w0       = (const float*)d_in[3];
    const float* b0       = (const float*)d_in[4];
    const float* w1       = (const float*)d_in[5];
    const float* b1       = (const float*)d_in[6];
    const float* attn_b   = (const float*)d_in[7];
    float* out = (float*)d_out;

    char* ws = (char*)d_ws;
    unsigned short* a_bf   = (unsigned short*)ws;                  // 38,535,168 B
    unsigned short* w0t    = (unsigned short*)(ws + 38535168);     //  3,211,264 B
    unsigned short* hidden = (unsigned short*)(ws + 41746432);     //  6,291,456 B (bf16)
    float*          kw     = (float*)(ws + 48037888);              //  1,204,224 B

    hipLaunchKernelGGL(ln_kernel,    dim3(BC),     dim3(256), 0, stream, x, ln_g, ln_b, a_bf);
    hipLaunchKernelGGL(w0t_kernel,   dim3(49, 8),  dim3(256), 0, stream, w0, w0t);
    hipLaunchKernelGGL(gemm1_kernel, dim3(96, 8),  dim3(256), 0, stream, a_bf, w0t, b0, hidden);
    hipLaunchKernelGGL(gemm2_kernel, dim3(BC / 4), dim3(256), 0, stream, hidden, w1, b1, kw);
    hipLaunchKernelGGL(conv_kernel,  dim3(BC / 2), dim3(256), 0, stream, x, kw, attn_b, out);
}